// Round 1
// baseline (22184.183 us; speedup 1.0000x reference)
//
#include <hip/hip_runtime.h>
#include <math.h>

// Decoder: 2-layer GRU (D=256 -> H=1024 -> H=1024) + FC head 1024->1024->512->256
// with LayerNorm+GELU(exact) between FC layers, softmax output fed back as input.
// T=64 steps, B=256 batch. Round 1: correct fp32 baseline, modular kernels.

#define B_ 256
#define H_ 1024
#define D_ 256
#define T_ 64

// ---------------------------------------------------------------------------
// Tiled fp32 GEMM: C[M,N] = A[M,K] @ W[N,K]^T + bias[N]
// 64x64 tile, 256 threads, 4x4 micro-tile, BK=16.
// ---------------------------------------------------------------------------
__global__ __launch_bounds__(256) void gemm_bias(
    const float* __restrict__ A, const float* __restrict__ W,
    const float* __restrict__ bias, float* __restrict__ C,
    int M, int N, int K)
{
    __shared__ float As[16][64];   // [k][m]
    __shared__ float Ws[16][64];   // [k][n]
    const int bm = blockIdx.y * 64;
    const int bn = blockIdx.x * 64;
    const int tid = threadIdx.x;
    const int tx = tid & 15, ty = tid >> 4;

    float bv[4];
#pragma unroll
    for (int j = 0; j < 4; j++) bv[j] = bias[bn + tx * 4 + j];

    float acc[4][4];
#pragma unroll
    for (int i = 0; i < 4; i++)
#pragma unroll
        for (int j = 0; j < 4; j++) acc[i][j] = 0.f;

    const int lm = tid >> 2;        // 0..63 : tile row
    const int lk = (tid & 3) * 4;   // 0,4,8,12 : k offset

    for (int k0 = 0; k0 < K; k0 += 16) {
        float4 a4 = *(const float4*)(A + (size_t)(bm + lm) * K + k0 + lk);
        float4 w4 = *(const float4*)(W + (size_t)(bn + lm) * K + k0 + lk);
        __syncthreads();
        As[lk + 0][lm] = a4.x; As[lk + 1][lm] = a4.y;
        As[lk + 2][lm] = a4.z; As[lk + 3][lm] = a4.w;
        Ws[lk + 0][lm] = w4.x; Ws[lk + 1][lm] = w4.y;
        Ws[lk + 2][lm] = w4.z; Ws[lk + 3][lm] = w4.w;
        __syncthreads();
#pragma unroll
        for (int k = 0; k < 16; k++) {
            float4 av = *(const float4*)&As[k][ty * 4];
            float4 wv = *(const float4*)&Ws[k][tx * 4];
            float am[4] = {av.x, av.y, av.z, av.w};
            float wn[4] = {wv.x, wv.y, wv.z, wv.w};
#pragma unroll
            for (int i = 0; i < 4; i++)
#pragma unroll
                for (int j = 0; j < 4; j++) acc[i][j] += am[i] * wn[j];
        }
    }
#pragma unroll
    for (int i = 0; i < 4; i++) {
        float4 o;
        o.x = acc[i][0] + bv[0]; o.y = acc[i][1] + bv[1];
        o.z = acc[i][2] + bv[2]; o.w = acc[i][3] + bv[3];
        *(float4*)(C + (size_t)(bm + ty * 4 + i) * N + bn + tx * 4) = o;
    }
}

// ---------------------------------------------------------------------------
// GRU gate combine: h = (1-z)*n + z*h with r,z,n from gi/gh [B,3H] (PyTorch order)
// ---------------------------------------------------------------------------
__global__ __launch_bounds__(256) void gru_combine(
    const float* __restrict__ gi, const float* __restrict__ gh,
    float* __restrict__ h)
{
    const int idx = blockIdx.x * 256 + threadIdx.x;   // over B*H = 262144
    const int m = idx >> 10, c = idx & 1023;
    const float* gim = gi + (size_t)m * 3072;
    const float* ghm = gh + (size_t)m * 3072;
    float r = 1.f / (1.f + expf(-(gim[c] + ghm[c])));
    float z = 1.f / (1.f + expf(-(gim[1024 + c] + ghm[1024 + c])));
    float n = tanhf(gim[2048 + c] + r * ghm[2048 + c]);
    h[idx] = (1.f - z) * n + z * h[idx];
}

// ---------------------------------------------------------------------------
// Block-wide sum reduce (256 threads = 4 waves of 64)
// ---------------------------------------------------------------------------
__device__ __forceinline__ float block_reduce_sum(float v, float* red)
{
#pragma unroll
    for (int o = 32; o > 0; o >>= 1) v += __shfl_xor(v, o, 64);
    const int wid = threadIdx.x >> 6;
    if ((threadIdx.x & 63) == 0) red[wid] = v;
    __syncthreads();
    float s = red[0] + red[1] + red[2] + red[3];
    __syncthreads();
    return s;
}

// ---------------------------------------------------------------------------
// LayerNorm (biased var, eps=1e-5) then exact GELU. One row per block.
// ---------------------------------------------------------------------------
template <int N>
__global__ __launch_bounds__(256) void ln_gelu(
    const float* __restrict__ X, const float* __restrict__ g,
    const float* __restrict__ b, float* __restrict__ Y)
{
    __shared__ float red[4];
    const int row = blockIdx.x;
    const int tid = threadIdx.x;
    constexpr int PT = N / 256;
    float v[PT];
    float s = 0.f;
#pragma unroll
    for (int i = 0; i < PT; i++) {
        v[i] = X[(size_t)row * N + tid + i * 256];
        s += v[i];
    }
    const float mu = block_reduce_sum(s, red) * (1.f / N);
    float s2 = 0.f;
#pragma unroll
    for (int i = 0; i < PT; i++) { float d = v[i] - mu; s2 += d * d; }
    const float var = block_reduce_sum(s2, red) * (1.f / N);
    const float inv = rsqrtf(var + 1e-5f);
#pragma unroll
    for (int i = 0; i < PT; i++) {
        int c = tid + i * 256;
        float t = (v[i] - mu) * inv * g[c] + b[c];
        Y[(size_t)row * N + c] = 0.5f * t * (1.f + erff(t * 0.70710678118654752f));
    }
}

// ---------------------------------------------------------------------------
// fc3 (K=512, N=256) + softmax. Block = 4 rows (one wave per row).
// Lane l owns cols {l, l+64, l+128, l+192}.
// ---------------------------------------------------------------------------
__global__ __launch_bounds__(256) void fc3_softmax(
    const float* __restrict__ A, const float* __restrict__ W,
    const float* __restrict__ bias, float* __restrict__ outb,
    float* __restrict__ dout, int t)
{
    const int wid = threadIdx.x >> 6;
    const int lane = threadIdx.x & 63;
    const int row = blockIdx.x * 4 + wid;
    const float* a = A + (size_t)row * 512;
    float acc[4];
#pragma unroll
    for (int j = 0; j < 4; j++) acc[j] = bias[lane + 64 * j];
    for (int k = 0; k < 512; k += 4) {
        float4 a4 = *(const float4*)(a + k);   // wave-uniform
#pragma unroll
        for (int j = 0; j < 4; j++) {
            float4 w4 = *(const float4*)(W + (size_t)(lane + 64 * j) * 512 + k);
            acc[j] += a4.x * w4.x + a4.y * w4.y + a4.z * w4.z + a4.w * w4.w;
        }
    }
    float mx = fmaxf(fmaxf(acc[0], acc[1]), fmaxf(acc[2], acc[3]));
#pragma unroll
    for (int o = 32; o > 0; o >>= 1) mx = fmaxf(mx, __shfl_xor(mx, o, 64));
    float e[4], s = 0.f;
#pragma unroll
    for (int j = 0; j < 4; j++) { e[j] = expf(acc[j] - mx); s += e[j]; }
#pragma unroll
    for (int o = 32; o > 0; o >>= 1) s += __shfl_xor(s, o, 64);
    const float inv = 1.f / s;
#pragma unroll
    for (int j = 0; j < 4; j++) {
        float p = e[j] * inv;
        int c = lane + 64 * j;
        outb[(size_t)row * 256 + c] = p;
        dout[((size_t)row * 64 + t) * 256 + c] = p;   // out[b, t, d]
    }
}

// ---------------------------------------------------------------------------
// State init: h0 = hidden[0], h1 = hidden[1], out = 0 (ws is poisoned 0xAA)
// ---------------------------------------------------------------------------
__global__ __launch_bounds__(256) void init_state(
    const float* __restrict__ hidden, float* __restrict__ h0,
    float* __restrict__ h1, float* __restrict__ outb)
{
    int i = blockIdx.x * 256 + threadIdx.x;     // grid covers 262144
    h0[i] = hidden[i];
    h1[i] = hidden[262144 + i];
    if (i < 65536) outb[i] = 0.f;
}

extern "C" void kernel_launch(void* const* d_in, const int* in_sizes, int n_in,
                              void* d_out, int out_size, void* d_ws, size_t ws_size,
                              hipStream_t stream)
{
    const float* hidden = (const float*)d_in[0];
    const float* W_ih0  = (const float*)d_in[1];
    const float* W_hh0  = (const float*)d_in[2];
    const float* b_ih0  = (const float*)d_in[3];
    const float* b_hh0  = (const float*)d_in[4];
    const float* W_ih1  = (const float*)d_in[5];
    const float* W_hh1  = (const float*)d_in[6];
    const float* b_ih1  = (const float*)d_in[7];
    const float* b_hh1  = (const float*)d_in[8];
    const float* fc1_w  = (const float*)d_in[9];
    const float* fc1_b  = (const float*)d_in[10];
    const float* ln1_g  = (const float*)d_in[11];
    const float* ln1_b  = (const float*)d_in[12];
    const float* fc2_w  = (const float*)d_in[13];
    const float* fc2_b  = (const float*)d_in[14];
    const float* ln2_g  = (const float*)d_in[15];
    const float* ln2_b  = (const float*)d_in[16];
    const float* fc3_w  = (const float*)d_in[17];
    const float* fc3_b  = (const float*)d_in[18];
    float* dout = (float*)d_out;

    // Workspace layout (floats): total 2,949,120 floats = 11.8 MB
    float* ws   = (float*)d_ws;
    float* h0   = ws;                 // 262144
    float* h1   = h0 + 262144;        // 262144
    float* outb = h1 + 262144;        // 65536
    float* gi   = outb + 65536;       // 786432
    float* gh   = gi + 786432;        // 786432
    float* a1r  = gh + 786432;        // 262144
    float* a1   = a1r + 262144;       // 262144
    float* a2r  = a1 + 262144;        // 131072
    float* a2   = a2r + 131072;       // 131072

    init_state<<<1024, 256, 0, stream>>>(hidden, h0, h1, outb);

    for (int t = 0; t < 64; t++) {
        // GRU layer 0: gh0 from old h0, gi0 from fed-back softmax out
        gemm_bias<<<dim3(48, 4), 256, 0, stream>>>(h0,  W_hh0, b_hh0, gh, 256, 3072, 1024);
        gemm_bias<<<dim3(48, 4), 256, 0, stream>>>(outb, W_ih0, b_ih0, gi, 256, 3072, 256);
        gru_combine<<<1024, 256, 0, stream>>>(gi, gh, h0);
        // GRU layer 1: gh1 from old h1, gi1 from new h0
        gemm_bias<<<dim3(48, 4), 256, 0, stream>>>(h1, W_hh1, b_hh1, gh, 256, 3072, 1024);
        gemm_bias<<<dim3(48, 4), 256, 0, stream>>>(h0, W_ih1, b_ih1, gi, 256, 3072, 1024);
        gru_combine<<<1024, 256, 0, stream>>>(gi, gh, h1);
        // FC head
        gemm_bias<<<dim3(16, 4), 256, 0, stream>>>(h1, fc1_w, fc1_b, a1r, 256, 1024, 1024);
        ln_gelu<1024><<<256, 256, 0, stream>>>(a1r, ln1_g, ln1_b, a1);
        gemm_bias<<<dim3(8, 4), 256, 0, stream>>>(a1, fc2_w, fc2_b, a2r, 256, 512, 1024);
        ln_gelu<512><<<256, 256, 0, stream>>>(a2r, ln2_g, ln2_b, a2);
        fc3_softmax<<<64, 256, 0, stream>>>(a2, fc3_w, fc3_b, outb, dout, t);
    }
}

// Round 2
// 6486.296 us; speedup vs baseline: 3.4202x; 3.4202x over previous
//
#include <hip/hip_runtime.h>
#include <math.h>

typedef __bf16 bf16_t;
typedef __bf16 bf16x8 __attribute__((ext_vector_type(8)));
typedef float f32x4 __attribute__((ext_vector_type(4)));

#define B_ 256
#define H_ 1024

// ---------------------------------------------------------------------------
// MFMA GEMM: C[M,N] = A[M,K](bf16) @ W[N,K](bf16)^T (+bias)
// Tile: (NW*16) x 64, BK=32. NW waves, wave w computes rows [w*16,w*16+16) x 64 cols.
// EPI 0: C fp32 = acc + bias.
// EPI 1: GRU combine epilogue. n-tiles j=0..3 are gates r,z,i_n,h_n of channels
//        c = (bn>>2)+col (weights pre-reordered by build_w4). Updates hf in
//        place, writes bf16 h to d1/d2.
// ---------------------------------------------------------------------------
template<int NW, int EPI>
__global__ __launch_bounds__(NW * 64) void gemm_mfma(
    const bf16_t* __restrict__ A, const bf16_t* __restrict__ W,
    const float* __restrict__ bias, int K,
    float* __restrict__ C, int ldc,
    float* __restrict__ hf,
    bf16_t* __restrict__ d1, int ld1, int off1,
    bf16_t* __restrict__ d2, int ld2, int off2)
{
    constexpr int MT = NW * 16;
    constexpr int R = 4 / NW;              // B-row loads per thread
    __shared__ __align__(16) bf16_t ldsA[MT * 40];
    __shared__ __align__(16) bf16_t ldsB[64 * 40];

    int bx = blockIdx.x, by = blockIdx.y;
    if (EPI == 1) {
        // grid is (64,4): remap so XCD x (round-robin by dispatch id &7) gets
        // n-blocks [x*8, x*8+8) -> its W4 slice (<=2MB) stays L2-resident.
        int d = by * 64 + bx;
        bx = (d & 7) * 8 + ((d >> 3) & 7);
        by = d >> 6;
    }
    const int bm = by * MT, bn = bx * 64;
    const int tid = threadIdx.x;

    // staging: thread -> (row tid>>2, 16B chunk tid&3)
    const int srow = tid >> 2, schk = tid & 3;
    const bf16_t* gA = A + (size_t)(bm + srow) * K + schk * 8;
    const bf16_t* gW = W + (size_t)(bn + srow) * K + schk * 8;
    const unsigned sa = srow * 40 + schk * 8;       // LDS elem offset

    const int lane = tid & 63, wv = tid >> 6;
    const int quad = lane >> 4, col = lane & 15;
    const unsigned ra_off = (wv * 16 + col) * 40 + quad * 8;
    const unsigned rb_off = col * 40 + quad * 8;

    f32x4 acc[4];
#pragma unroll
    for (int j = 0; j < 4; j++)
#pragma unroll
        for (int e = 0; e < 4; e++) acc[j][e] = 0.f;

    int4 pa, pb[R];
    pa = *(const int4*)gA;
#pragma unroll
    for (int r = 0; r < R; r++) pb[r] = *(const int4*)(gW + (size_t)(r * MT) * K);
    gA += 32; gW += 32;

    const int nch = K >> 5;
    for (int c = 0; c < nch; ++c) {
        __syncthreads();
        *(int4*)(ldsA + sa) = pa;
#pragma unroll
        for (int r = 0; r < R; r++) *(int4*)(ldsB + sa + r * MT * 40) = pb[r];
        __syncthreads();
        if (c + 1 < nch) {
            pa = *(const int4*)gA;
#pragma unroll
            for (int r = 0; r < R; r++) pb[r] = *(const int4*)(gW + (size_t)(r * MT) * K);
            gA += 32; gW += 32;
        }
        bf16x8 af = *(const bf16x8*)(ldsA + ra_off);
        bf16x8 b0 = *(const bf16x8*)(ldsB + rb_off);
        bf16x8 b1 = *(const bf16x8*)(ldsB + rb_off + 16 * 40);
        bf16x8 b2 = *(const bf16x8*)(ldsB + rb_off + 32 * 40);
        bf16x8 b3 = *(const bf16x8*)(ldsB + rb_off + 48 * 40);
        acc[0] = __builtin_amdgcn_mfma_f32_16x16x32_bf16(af, b0, acc[0], 0, 0, 0);
        acc[1] = __builtin_amdgcn_mfma_f32_16x16x32_bf16(af, b1, acc[1], 0, 0, 0);
        acc[2] = __builtin_amdgcn_mfma_f32_16x16x32_bf16(af, b2, acc[2], 0, 0, 0);
        acc[3] = __builtin_amdgcn_mfma_f32_16x16x32_bf16(af, b3, acc[3], 0, 0, 0);
    }

    if (EPI == 0) {
#pragma unroll
        for (int j = 0; j < 4; j++) {
            const int n = bn + j * 16 + col;
            const float bj = bias[n];
#pragma unroll
            for (int r = 0; r < 4; r++) {
                const int m = bm + wv * 16 + quad * 4 + r;
                C[(size_t)m * ldc + n] = acc[j][r] + bj;
            }
        }
    } else {
        const int cch = (bn >> 2) + col;   // channel index
        const float br  = bias[bn + col];
        const float bz  = bias[bn + 16 + col];
        const float bin = bias[bn + 32 + col];
        const float bhn = bias[bn + 48 + col];
#pragma unroll
        for (int r = 0; r < 4; r++) {
            const int m = bm + wv * 16 + quad * 4 + r;
            const float gr  = acc[0][r] + br;
            const float gz  = acc[1][r] + bz;
            const float gin = acc[2][r] + bin;
            const float ghn = acc[3][r] + bhn;
            const float rr = 1.f / (1.f + __expf(-gr));
            const float zz = 1.f / (1.f + __expf(-gz));
            const float nn = tanhf(gin + rr * ghn);
            const size_t hidx = (size_t)m * 1024 + cch;
            const float hnew = (1.f - zz) * nn + zz * hf[hidx];
            hf[hidx] = hnew;
            const bf16_t hb = (bf16_t)hnew;
            d1[(size_t)m * ld1 + off1 + cch] = hb;
            d2[(size_t)m * ld2 + off2 + cch] = hb;
        }
    }
}

// ---------------------------------------------------------------------------
// Build fused GRU weight matrix W4[4096, K] (K = Kx + 1024), bf16, with row
// order n' = (c>>4)*64 + g*16 + (c&15); g: 0=r, 1=z, 2=i_n (x only), 3=h_n
// (h only). Also builds fused bias b4.
// ---------------------------------------------------------------------------
__global__ __launch_bounds__(256) void build_w4(
    const float* __restrict__ Wih, const float* __restrict__ Whh,
    const float* __restrict__ bih, const float* __restrict__ bhh,
    bf16_t* __restrict__ W4, float* __restrict__ b4, int Kx)
{
    const int K = Kx + 1024;
    const int tpr = K >> 2;
    const int idx = blockIdx.x * 256 + threadIdx.x;   // over 4096*tpr, exact
    const int np = idx / tpr;
    const int k4 = (idx - np * tpr) * 4;
    const int c = ((np >> 6) << 4) + (np & 15);
    const int g = (np >> 4) & 3;
    const int srow = (g == 0 ? c : (g == 1 ? 1024 + c : 2048 + c));
    float4 v = make_float4(0.f, 0.f, 0.f, 0.f);
    if (k4 < Kx) {
        if (g != 3) v = *(const float4*)(Wih + (size_t)srow * Kx + k4);
    } else {
        if (g != 2) v = *(const float4*)(Whh + (size_t)srow * 1024 + (k4 - Kx));
    }
    bf16_t* dst = W4 + (size_t)np * K + k4;
    dst[0] = (bf16_t)v.x; dst[1] = (bf16_t)v.y;
    dst[2] = (bf16_t)v.z; dst[3] = (bf16_t)v.w;
    if (k4 == 0) {
        b4[np] = (g == 0) ? bih[c] + bhh[c]
               : (g == 1) ? bih[1024 + c] + bhh[1024 + c]
               : (g == 2) ? bih[2048 + c] : bhh[2048 + c];
    }
}

// fp32 -> bf16 convert (4 elems/thread, exact grid)
__global__ __launch_bounds__(256) void conv_bf16(
    const float* __restrict__ src, bf16_t* __restrict__ dst)
{
    const int i4 = (blockIdx.x * 256 + threadIdx.x) * 4;
    float4 v = *(const float4*)(src + i4);
    dst[i4 + 0] = (bf16_t)v.x; dst[i4 + 1] = (bf16_t)v.y;
    dst[i4 + 2] = (bf16_t)v.z; dst[i4 + 3] = (bf16_t)v.w;
}

// ---------------------------------------------------------------------------
// init: h0f/h1f fp32 state, A0[0] = [bf16(0) | bf16(h0)], A1[0][:,1024:] = bf16(h1)
// ---------------------------------------------------------------------------
__global__ __launch_bounds__(256) void init_state(
    const float* __restrict__ hidden, float* __restrict__ h0f,
    float* __restrict__ h1f, bf16_t* __restrict__ A0_0, bf16_t* __restrict__ A1_0)
{
    const int i = blockIdx.x * 256 + threadIdx.x;   // over 262144
    const int m = i >> 10, c = i & 1023;
    const float h0 = hidden[i], h1 = hidden[262144 + i];
    h0f[i] = h0; h1f[i] = h1;
    A0_0[(size_t)m * 1280 + 256 + c] = (bf16_t)h0;
    A1_0[(size_t)m * 2048 + 1024 + c] = (bf16_t)h1;
    if (c < 256) A0_0[(size_t)m * 1280 + c] = (bf16_t)0.f;
}

// ---------------------------------------------------------------------------
// LayerNorm + exact GELU, bf16 output. One row per 256-thread block.
// ---------------------------------------------------------------------------
__device__ __forceinline__ float block_reduce_sum(float v, float* red)
{
#pragma unroll
    for (int o = 32; o > 0; o >>= 1) v += __shfl_xor(v, o, 64);
    const int wid = threadIdx.x >> 6;
    if ((threadIdx.x & 63) == 0) red[wid] = v;
    __syncthreads();
    float s = red[0] + red[1] + red[2] + red[3];
    __syncthreads();
    return s;
}

template <int N>
__global__ __launch_bounds__(256) void ln_gelu(
    const float* __restrict__ X, const float* __restrict__ g,
    const float* __restrict__ b, bf16_t* __restrict__ Y)
{
    __shared__ float red[4];
    const int row = blockIdx.x;
    const int tid = threadIdx.x;
    constexpr int PT = N / 256;
    float v[PT];
    float s = 0.f;
#pragma unroll
    for (int i = 0; i < PT; i++) {
        v[i] = X[(size_t)row * N + tid + i * 256];
        s += v[i];
    }
    const float mu = block_reduce_sum(s, red) * (1.f / N);
    float s2 = 0.f;
#pragma unroll
    for (int i = 0; i < PT; i++) { float d = v[i] - mu; s2 += d * d; }
    const float var = block_reduce_sum(s2, red) * (1.f / N);
    const float inv = rsqrtf(var + 1e-5f);
#pragma unroll
    for (int i = 0; i < PT; i++) {
        const int c = tid + i * 256;
        const float t = (v[i] - mu) * inv * g[c] + b[c];
        Y[(size_t)row * N + c] = (bf16_t)(0.5f * t * (1.f + erff(t * 0.70710678118654752f)));
    }
}

// ---------------------------------------------------------------------------
// softmax over logits rows; writes dout[b,t,:] fp32 and feedback bf16 into A0
// ---------------------------------------------------------------------------
__global__ __launch_bounds__(256) void softmax_fb(
    const float* __restrict__ logits, float* __restrict__ dout,
    bf16_t* __restrict__ a0w, int t)
{
    const int wv = threadIdx.x >> 6, lane = threadIdx.x & 63;
    const int row = blockIdx.x * 4 + wv;
    float v[4];
#pragma unroll
    for (int j = 0; j < 4; j++) v[j] = logits[(size_t)row * 256 + lane + 64 * j];
    float mx = fmaxf(fmaxf(v[0], v[1]), fmaxf(v[2], v[3]));
#pragma unroll
    for (int o = 32; o > 0; o >>= 1) mx = fmaxf(mx, __shfl_xor(mx, o, 64));
    float e[4], s = 0.f;
#pragma unroll
    for (int j = 0; j < 4; j++) { e[j] = expf(v[j] - mx); s += e[j]; }
#pragma unroll
    for (int o = 32; o > 0; o >>= 1) s += __shfl_xor(s, o, 64);
    const float inv = 1.f / s;
#pragma unroll
    for (int j = 0; j < 4; j++) {
        const float p = e[j] * inv;
        const int c = lane + 64 * j;
        dout[((size_t)row * 64 + t) * 256 + c] = p;
        a0w[(size_t)row * 1280 + c] = (bf16_t)p;
    }
}

extern "C" void kernel_launch(void* const* d_in, const int* in_sizes, int n_in,
                              void* d_out, int out_size, void* d_ws, size_t ws_size,
                              hipStream_t stream)
{
    const float* hidden = (const float*)d_in[0];
    const float* W_ih0  = (const float*)d_in[1];
    const float* W_hh0  = (const float*)d_in[2];
    const float* b_ih0  = (const float*)d_in[3];
    const float* b_hh0  = (const float*)d_in[4];
    const float* W_ih1  = (const float*)d_in[5];
    const float* W_hh1  = (const float*)d_in[6];
    const float* b_ih1  = (const float*)d_in[7];
    const float* b_hh1  = (const float*)d_in[8];
    const float* fc1_w  = (const float*)d_in[9];
    const float* fc1_b  = (const float*)d_in[10];
    const float* ln1_g  = (const float*)d_in[11];
    const float* ln1_b  = (const float*)d_in[12];
    const float* fc2_w  = (const float*)d_in[13];
    const float* fc2_b  = (const float*)d_in[14];
    const float* ln2_g  = (const float*)d_in[15];
    const float* ln2_b  = (const float*)d_in[16];
    const float* fc3_w  = (const float*)d_in[17];
    const float* fc3_b  = (const float*)d_in[18];
    float* dout = (float*)d_out;

    char* p = (char*)d_ws;
    auto alloc = [&](size_t bytes) { void* r = (void*)p; p += (bytes + 255) & ~(size_t)255; return r; };
    float*  h0f   = (float*)alloc(262144 * 4);
    float*  h1f   = (float*)alloc(262144 * 4);
    bf16_t* A0[2] = { (bf16_t*)alloc(256 * 1280 * 2), (bf16_t*)alloc(256 * 1280 * 2) };
    bf16_t* A1[2] = { (bf16_t*)alloc(256 * 2048 * 2), (bf16_t*)alloc(256 * 2048 * 2) };
    bf16_t* h1b   = (bf16_t*)alloc(262144 * 2);
    float*  a1r   = (float*)alloc(262144 * 4);
    bf16_t* a1b   = (bf16_t*)alloc(262144 * 2);
    float*  a2r   = (float*)alloc(131072 * 4);
    bf16_t* a2b   = (bf16_t*)alloc(131072 * 2);
    float*  logits= (float*)alloc(65536 * 4);
    float*  b4_0  = (float*)alloc(4096 * 4);
    float*  b4_1  = (float*)alloc(4096 * 4);
    bf16_t* W4_0  = (bf16_t*)alloc((size_t)4096 * 1280 * 2);
    bf16_t* W4_1  = (bf16_t*)alloc((size_t)4096 * 2048 * 2);
    bf16_t* fc1wb = (bf16_t*)alloc((size_t)1048576 * 2);
    bf16_t* fc2wb = (bf16_t*)alloc((size_t)524288 * 2);
    bf16_t* fc3wb = (bf16_t*)alloc((size_t)131072 * 2);

    // weight prep (runs every launch; ~40us total, graph-safe)
    build_w4<<<5120, 256, 0, stream>>>(W_ih0, W_hh0, b_ih0, b_hh0, W4_0, b4_0, 256);
    build_w4<<<8192, 256, 0, stream>>>(W_ih1, W_hh1, b_ih1, b_hh1, W4_1, b4_1, 1024);
    conv_bf16<<<1024, 256, 0, stream>>>(fc1_w, fc1wb);
    conv_bf16<<<512, 256, 0, stream>>>(fc2_w, fc2wb);
    conv_bf16<<<128, 256, 0, stream>>>(fc3_w, fc3wb);
    init_state<<<1024, 256, 0, stream>>>(hidden, h0f, h1f, A0[0], A1[0]);

    for (int t = 0; t < 64; t++) {
        bf16_t* A0r = A0[t & 1];
        bf16_t* A0w = A0[(t + 1) & 1];
        bf16_t* A1r = A1[t & 1];
        bf16_t* A1w = A1[(t + 1) & 1];

        // GRU layer 0 (fused GEMM + combine): reads A0r=[out|h0], updates h0f,
        // writes bf16 h0 into A1r[:, :1024] (gru1 reads this step) and
        // A0w[:, 256:1280] (gru0 reads next step).
        gemm_mfma<4, 1><<<dim3(64, 4), 256, 0, stream>>>(
            A0r, W4_0, b4_0, 1280, nullptr, 0,
            h0f, A1r, 2048, 0, A0w, 1280, 256);
        // GRU layer 1: reads A1r=[h0_new|h1_old], updates h1f, writes bf16 h1
        // into A1w[:, 1024:] (next step) and h1b (fc1 input).
        gemm_mfma<4, 1><<<dim3(64, 4), 256, 0, stream>>>(
            A1r, W4_1, b4_1, 2048, nullptr, 0,
            h1f, A1w, 2048, 1024, h1b, 1024, 0);
        // FC head
        gemm_mfma<2, 0><<<dim3(16, 8), 128, 0, stream>>>(
            h1b, fc1wb, fc1_b, 1024, a1r, 1024, nullptr, nullptr, 0, 0, nullptr, 0, 0);
        ln_gelu<1024><<<256, 256, 0, stream>>>(a1r, ln1_g, ln1_b, a1b);
        gemm_mfma<2, 0><<<dim3(8, 8), 128, 0, stream>>>(
            a1b, fc2wb, fc2_b, 1024, a2r, 512, nullptr, nullptr, 0, 0, nullptr, 0, 0);
        ln_gelu<512><<<256, 256, 0, stream>>>(a2r, ln2_g, ln2_b, a2b);
        gemm_mfma<2, 0><<<dim3(4, 8), 128, 0, stream>>>(
            a2b, fc3wb, fc3_b, 512, logits, 256, nullptr, nullptr, 0, 0, nullptr, 0, 0);
        softmax_fb<<<64, 256, 0, stream>>>(logits, dout, A0w, t);
    }
}